// Round 1
// 2328.070 us; speedup vs baseline: 1.0023x; 1.0023x over previous
//
#include <hip/hip_runtime.h>
#include <stdint.h>

// Problem constants
#define B_TOT   4096          // 4*1024 batch rows
#define D_IN    2048
#define D_OUT   2048
#define NCHUNK  4
#define LIN     512
#define LOUT    512
#define RK      8             // ring rank R
#define CORE_R_STRIDE 2097152 // LOUT*LIN*RK
#define CORE_O_STRIDE 4096    // LIN*RK

// Workspace layout (floats)
#define WS_XT    0                            // xT [2048][4096]           : 8388608
#define WS_GHAT  8388608                      // Ghat [4][8][512][8]       : 131072
#define WS_S     (8388608 + 131072)           // S    [4][4096][64]        : 1048576
#define WS_ENVT  (8388608 + 131072 + 1048576) // envT [4][64][4096]        : 1048576
#define WS_GSPL  (8388608 + 131072 + 1048576 + 1048576) // split-G planes (shorts)
#define GSPL_PLANE 67108864ull                // shorts per plane (hi or lo) = 4*8*512*4096
#define GSPL_CHUNK 16777216ull                // shorts per chunk within a plane
#define WS_NEED_BYTES 310902784ull            // (WS_GSPL*4 + 2 planes * 2B)

typedef __attribute__((ext_vector_type(8))) __bf16 bf16x8;
typedef __attribute__((ext_vector_type(4))) float f32x4;
typedef __attribute__((ext_vector_type(4))) unsigned int u32x4;

// ---------------- Kernel 1: transpose x [4096][2048] -> xT [2048][4096] --------
__global__ __launch_bounds__(256) void k_transpose(const float* __restrict__ x,
                                                   float* __restrict__ xT) {
    __shared__ float tile[32][33];
    int b0 = blockIdx.x * 32;
    int c0 = blockIdx.y * 32;
    int tx = threadIdx.x;      // 0..31
    int ty = threadIdx.y;      // 0..7
#pragma unroll
    for (int j = 0; j < 4; ++j)
        tile[ty + j * 8][tx] = x[(size_t)(b0 + ty + j * 8) * D_IN + c0 + tx];
    __syncthreads();
#pragma unroll
    for (int j = 0; j < 4; ++j)
        xT[(size_t)(c0 + ty + j * 8) * B_TOT + b0 + tx] = tile[tx][ty + j * 8];
}

// ---------------- Kernel 2: Ghat[i][r][xs] = sum_o G_i[r][o][xs] ---------------
__global__ __launch_bounds__(256) void k_reduce_g(const float* __restrict__ g0,
                                                  const float* __restrict__ g1,
                                                  const float* __restrict__ g2,
                                                  const float* __restrict__ g3,
                                                  float* __restrict__ ghat) {
    int i = blockIdx.z;
    int r = blockIdx.y;
    int xs = blockIdx.x * 256 + threadIdx.x;   // 0..4095
    const float* G = (i == 0) ? g0 : (i == 1) ? g1 : (i == 2) ? g2 : g3;
    const float* base = G + (size_t)r * CORE_R_STRIDE + xs;
    float acc = 0.f;
#pragma unroll 8
    for (int o = 0; o < LOUT; ++o) acc += base[(size_t)o * CORE_O_STRIDE];
    ghat[(size_t)i * 32768 + r * 4096 + xs] = acc;
}

// ---------------- Kernel 3: S[i][b][r*8+s] = sum_x Ghat[i][r][x][s]*x[b][i*512+x]
__global__ __launch_bounds__(256) void k_s(const float* __restrict__ x,
                                           const float* __restrict__ ghat,
                                           float* __restrict__ S) {
    int i = blockIdx.y;
    int tid = threadIdx.x;
    int rs = tid & 63;
    int b = blockIdx.x * 4 + (tid >> 6);
    int r = rs >> 3, s = rs & 7;
    const float* gh = ghat + (size_t)i * 32768 + r * 4096 + s;
    const float* xr = x + (size_t)b * D_IN + i * LIN;
    float acc = 0.f;
#pragma unroll 8
    for (int xi = 0; xi < LIN; ++xi) acc = fmaf(gh[xi * 8], xr[xi], acc);
    S[(size_t)i * (B_TOT * 64) + b * 64 + rs] = acc;
}

// ---------------- Kernel 4: chain products -> envT ----------------------------
__device__ __forceinline__ float mm8(float A, float B, int lane) {
    float c = 0.f;
#pragma unroll
    for (int p = 0; p < 8; ++p) {
        float a = __shfl(A, (lane & 56) | p, 64);
        float b = __shfl(B, (p << 3) | (lane & 7), 64);
        c = fmaf(a, b, c);
    }
    return c;
}
__device__ __forceinline__ float tr8(float E, int lane) {
    return __shfl(E, ((lane & 7) << 3) | (lane >> 3), 64);
}

__global__ __launch_bounds__(256) void k_env(const float* __restrict__ S,
                                             float* __restrict__ envT) {
    int tid = threadIdx.x;
    int lane = tid & 63;
    int b = blockIdx.x * 4 + (tid >> 6);
    float S0 = S[0 * (B_TOT * 64) + b * 64 + lane];
    float S1 = S[1 * (B_TOT * 64) + b * 64 + lane];
    float S2 = S[2 * (B_TOT * 64) + b * 64 + lane];
    float S3 = S[3 * (B_TOT * 64) + b * 64 + lane];

    float P1 = S0;
    float P2 = mm8(P1, S1, lane);
    float P3 = mm8(P2, S2, lane);
    float Q2 = S3;
    float Q1 = mm8(S2, Q2, lane);
    float Q0 = mm8(S1, Q1, lane);

    float e0 = tr8(Q0, lane);
    float e1 = tr8(mm8(Q1, P1, lane), lane);
    float e2 = tr8(mm8(Q2, P2, lane), lane);
    float e3 = tr8(P3, lane);

    envT[(size_t)(0 * 64 + lane) * B_TOT + b] = e0;
    envT[(size_t)(1 * 64 + lane) * B_TOT + b] = e1;
    envT[(size_t)(2 * 64 + lane) * B_TOT + b] = e2;
    envT[(size_t)(3 * 64 + lane) * B_TOT + b] = e3;
}

// ---------------- split helper: two fp32 -> packed bf16 hi pair + lo pair ------
__device__ __forceinline__ uint2 split2(float a, float b) {
    unsigned int ua = __float_as_uint(a), ub = __float_as_uint(b);
    unsigned int h = (ub & 0xffff0000u) | (ua >> 16);
    float la = a - __uint_as_float(ua & 0xffff0000u);
    float lb = b - __uint_as_float(ub & 0xffff0000u);
    unsigned int l = (__float_as_uint(lb) & 0xffff0000u) | (__float_as_uint(la) >> 16);
    return make_uint2(h, l);
}

// ---------------- Kernel 4.5: precompute split-bf16 planes of G ----------------
// hi[i][r][o][k], lo[i][r][o][k] as bf16 bit patterns (shorts), k contiguous.
// G_i flat layout [r][o][k] matches plane layout, so this is a linear pass.
__global__ __launch_bounds__(256) void k_split_g(const float* __restrict__ g0,
                                                 const float* __restrict__ g1,
                                                 const float* __restrict__ g2,
                                                 const float* __restrict__ g3,
                                                 short* __restrict__ hi,
                                                 short* __restrict__ lo) {
    size_t e8 = ((size_t)blockIdx.x * 256 + threadIdx.x) * 8;  // elem index, 8/thread
    int i = (int)(e8 >> 24);                                   // 2^24 elems per chunk
    const float* G = (i == 0) ? g0 : (i == 1) ? g1 : (i == 2) ? g2 : g3;
    size_t off = e8 & (GSPL_CHUNK - 1);
    float4 f0 = *(const float4*)(G + off);
    float4 f1 = *(const float4*)(G + off + 4);
    u32x4 H, L;
    uint2 p;
    p = split2(f0.x, f0.y); H.x = p.x; L.x = p.y;
    p = split2(f0.z, f0.w); H.y = p.x; L.y = p.y;
    p = split2(f1.x, f1.y); H.z = p.x; L.z = p.y;
    p = split2(f1.z, f1.w); H.w = p.x; L.w = p.y;
    *(u32x4*)(hi + e8) = H;
    *(u32x4*)(lo + e8) = L;
}

// ---------------- async global->LDS (16B per lane, dest = wave base + lane*16) -
__device__ __forceinline__ void gld16(const void* g, void* l) {
    __builtin_amdgcn_global_load_lds(
        (const __attribute__((address_space(1))) void*)g,
        (__attribute__((address_space(3))) void*)l, 16, 0, 0);
}

// ---------------- Kernel 5 (new): MFMA GEMM from precomputed split-G -----------
// out_i = sum_r Z_{i,r} @ G_{i,r}^T, split-bf16 3-product emulation.
// BM=128 (b), BN=128 (o), BK=32 (k=(x,s)).
// B (=G hi/lo) staged via global_load_lds_dwordx4, double-buffered, ONE barrier
// per K-step, stage(t+1) issued before compute(t) so loads fly under the MFMAs.
// LDS layout [128 o][32 k] shorts with 16B-slot XOR swizzle slot^=((row>>1)&3),
// applied on the *global source* address (DMA dest must stay linear) and
// inverted on the ds_read address -> 2-way bank access (free).
// A (=env*x) generated in registers; x comes from per-lane register prefetch.
__global__ __launch_bounds__(256, 2) void k_gemm2(const short* __restrict__ ghi,
                                                  const short* __restrict__ glo,
                                                  const float* __restrict__ xT,
                                                  const float* __restrict__ envT,
                                                  const float* __restrict__ bias,
                                                  float* __restrict__ out) {
    int l = blockIdx.x;                       // 0..511
    int c = (l & 7) | ((l >> 8) << 3);        // combo 0..15 (XCD swizzle)
    int b_idx = (l >> 3) & 31;                // b-tile 0..31
    int i = c >> 2;                           // chunk
    int o0 = (c & 3) * 128;
    int b0 = b_idx * 128;

    const short* Hi = ghi + (size_t)i * GSPL_CHUNK;
    const short* Lo = glo + (size_t)i * GSPL_CHUNK;
    const float* xTi = xT + (size_t)i * LIN * B_TOT;
    const float* eTi = envT + (size_t)i * 64 * B_TOT;

    __shared__ __align__(16) short Bhi[2][4096];
    __shared__ __align__(16) short Blo[2][4096];

    const int tid = threadIdx.x;
    const int lane = tid & 63;
    const int wave = tid >> 6;
    const int wm = (wave >> 1) * 64;
    const int wn = (wave & 1) * 64;
    const int l15 = lane & 15;
    const int quad = lane >> 4;
    const int lq = lane >> 2;     // staging row-within-16
    const int ls = lane & 3;      // staging 16B slot
    const int w32 = wave * 32;

    f32x4 acc[4][4];
#pragma unroll
    for (int mf = 0; mf < 4; ++mf)
#pragma unroll
        for (int nf = 0; nf < 4; ++nf) acc[mf][nf] = (f32x4){0.f, 0.f, 0.f, 0.f};

    // stage K-step tn (t = r*128+kk) into buffer pb: 4 gload_lds per wave
    auto STAGE = [&](int tn, int pb) {
#pragma unroll
        for (int j = 0; j < 2; ++j) {
            int row = w32 + j * 16 + lq;                       // o row 0..127
            int sl = ls ^ ((row >> 1) & 3);                    // source 16B k-slot
            size_t soff = ((size_t)((tn >> 7) * 512 + o0 + row) << 12)
                        + (size_t)(tn & 127) * 32 + sl * 8;
            int doff = wave * 1024 + j * 512;                  // uniform wave base
            gld16(Hi + soff, &Bhi[pb][doff]);
            gld16(Lo + soff, &Blo[pb][doff]);
        }
    };

    // x register prefetch: xv[mf] = x[b = b0+wm+mf*16+l15][xrow = kk*4+quad]
    float xc[4], xn[4];
#pragma unroll
    for (int mf = 0; mf < 4; ++mf)
        xc[mf] = xTi[(size_t)quad * B_TOT + b0 + wm + mf * 16 + l15];

    STAGE(0, 0);
    __syncthreads();

    int t = 0;
    for (int r = 0; r < 8; ++r) {
        // env for this r: e[mf][s], held in registers for 128 K-steps
        float e[4][8];
#pragma unroll
        for (int mf = 0; mf < 4; ++mf) {
            int m = b0 + wm + mf * 16 + l15;
#pragma unroll
            for (int s = 0; s < 8; ++s)
                e[mf][s] = eTi[(size_t)(r * 8 + s) * B_TOT + m];
        }
        for (int kk = 0; kk < 128; ++kk, ++t) {
            const int p = t & 1;
            if (t + 1 < 1024) STAGE(t + 1, p ^ 1);
            // x prefetch for kk+1 (mod 128: x is r-independent, seam is free)
#pragma unroll
            for (int mf = 0; mf < 4; ++mf)
                xn[mf] = xTi[(size_t)(((kk + 1) & 127) * 4 + quad) * B_TOT
                             + b0 + wm + mf * 16 + l15];

            // ---- B fragments from LDS (inverse swizzle on slot) ----
            bf16x8 bh[4], bl[4];
#pragma unroll
            for (int nf = 0; nf < 4; ++nf) {
                int n = wn + nf * 16 + l15;
                int sl = quad ^ ((n >> 1) & 3);
                bh[nf] = *(const bf16x8*)&Bhi[p][n * 32 + sl * 8];
                bl[nf] = *(const bf16x8*)&Blo[p][n * 32 + sl * 8];
            }

            // ---- A fragments generated in registers + MFMA ----
#pragma unroll
            for (int mf = 0; mf < 4; ++mf) {
                float xv = xc[mf];
                u32x4 AH, AL;
                uint2 pr;
                pr = split2(e[mf][0] * xv, e[mf][1] * xv); AH.x = pr.x; AL.x = pr.y;
                pr = split2(e[mf][2] * xv, e[mf][3] * xv); AH.y = pr.x; AL.y = pr.y;
                pr = split2(e[mf][4] * xv, e[mf][5] * xv); AH.z = pr.x; AL.z = pr.y;
                pr = split2(e[mf][6] * xv, e[mf][7] * xv); AH.w = pr.x; AL.w = pr.y;
                bf16x8 Ah = __builtin_bit_cast(bf16x8, AH);
                bf16x8 Al = __builtin_bit_cast(bf16x8, AL);
#pragma unroll
                for (int nf = 0; nf < 4; ++nf) {
                    acc[mf][nf] = __builtin_amdgcn_mfma_f32_16x16x32_bf16(Ah, bh[nf], acc[mf][nf], 0, 0, 0);
                    acc[mf][nf] = __builtin_amdgcn_mfma_f32_16x16x32_bf16(Ah, bl[nf], acc[mf][nf], 0, 0, 0);
                    acc[mf][nf] = __builtin_amdgcn_mfma_f32_16x16x32_bf16(Al, bh[nf], acc[mf][nf], 0, 0, 0);
                }
            }
            __syncthreads();   // drains vmcnt: next buffer staged, this one reusable
#pragma unroll
            for (int mf = 0; mf < 4; ++mf) xc[mf] = xn[mf];
        }
    }

    // ---- epilogue: C/D layout col=lane&15, row=quad*4+reg ----
#pragma unroll
    for (int nf = 0; nf < 4; ++nf) {
        int col = o0 + wn + nf * 16 + l15;
        float bv = bias[i * LOUT + col];
#pragma unroll
        for (int mf = 0; mf < 4; ++mf) {
#pragma unroll
            for (int reg = 0; reg < 4; ++reg) {
                int row = b0 + wm + mf * 16 + quad * 4 + reg;
                out[(size_t)row * D_OUT + i * LOUT + col] = acc[mf][nf][reg] + bv;
            }
        }
    }
}

// ---------------- Kernel 5 (fallback): original on-the-fly split GEMM ----------
__global__ __launch_bounds__(256, 2) void k_gemm_mfma(const float* __restrict__ g0,
                                                      const float* __restrict__ g1,
                                                      const float* __restrict__ g2,
                                                      const float* __restrict__ g3,
                                                      const float* __restrict__ xT,
                                                      const float* __restrict__ envT,
                                                      const float* __restrict__ bias,
                                                      float* __restrict__ out) {
    int l = blockIdx.x;                       // 0..511
    int c = (l & 7) | (((l >> 3) >> 5) << 3); // combo 0..15
    int b_idx = (l >> 3) & 31;                // b-tile 0..31
    int i = c >> 2;                           // chunk
    int o0 = (c & 3) * 128;
    int b0 = b_idx * 128;

    const float* G = (i == 0) ? g0 : (i == 1) ? g1 : (i == 2) ? g2 : g3;
    const float* xTi = xT + (size_t)i * LIN * B_TOT;
    const float* eTi = envT + (size_t)i * 64 * B_TOT;

    __shared__ __align__(16) short Bhi[128 * 32];
    __shared__ __align__(16) short Blo[128 * 32];
    __shared__ float Xs[4][160];

    const int tid = threadIdx.x;
    const int lane = tid & 63;
    const int wave = tid >> 6;
    const int wm = (wave >> 1) * 64;
    const int wn = (wave & 1) * 64;
    const int l15 = lane & 15;
    const int quad = lane >> 4;

    f32x4 acc[4][4];
#pragma unroll
    for (int mf = 0; mf < 4; ++mf)
#pragma unroll
        for (int nf = 0; nf < 4; ++nf) acc[mf][nf] = (f32x4){0.f, 0.f, 0.f, 0.f};

    const int so = tid >> 1;
    const int sh = (tid & 1) * 16;
    const float* gbase = G + (size_t)(o0 + so) * CORE_O_STRIDE + sh;

    for (int r = 0; r < 8; ++r) {
        float e[4][8];
#pragma unroll
        for (int mf = 0; mf < 4; ++mf) {
            int m = b0 + wm + mf * 16 + l15;
#pragma unroll
            for (int s = 0; s < 8; ++s)
                e[mf][s] = eTi[(size_t)(r * 8 + s) * B_TOT + m];
        }
        const float* Gr = gbase + (size_t)r * CORE_R_STRIDE;

        for (int kk = 0; kk < 128; ++kk) {
            const int k0 = kk * 32;
            __syncthreads();
            if (tid < 128) {
                int xr = tid >> 5, bc = (tid & 31) * 4;
                *(float4*)&Xs[xr][bc] =
                    *(const float4*)&xTi[(size_t)(kk * 4 + xr) * B_TOT + b0 + bc];
            }
            {
                float4 f0 = *(const float4*)&Gr[k0 + 0];
                float4 f1 = *(const float4*)&Gr[k0 + 4];
                float4 f2 = *(const float4*)&Gr[k0 + 8];
                float4 f3 = *(const float4*)&Gr[k0 + 12];
                u32x4 H0, L0, H1, L1;
                uint2 p;
                p = split2(f0.x, f0.y); H0.x = p.x; L0.x = p.y;
                p = split2(f0.z, f0.w); H0.y = p.x; L0.y = p.y;
                p = split2(f1.x, f1.y); H0.z = p.x; L0.z = p.y;
                p = split2(f1.z, f1.w); H0.w = p.x; L0.w = p.y;
                p = split2(f2.x, f2.y); H1.x = p.x; L1.x = p.y;
                p = split2(f2.z, f2.w); H1.y = p.x; L1.y = p.y;
                p = split2(f3.x, f3.y); H1.z = p.x; L1.z = p.y;
                p = split2(f3.z, f3.w); H1.w = p.x; L1.w = p.y;
                *(u32x4*)&Bhi[so * 32 + sh] = H0;
                *(u32x4*)&Bhi[so * 32 + sh + 8] = H1;
                *(u32x4*)&Blo[so * 32 + sh] = L0;
                *(u32x4*)&Blo[so * 32 + sh + 8] = L1;
            }
            __syncthreads();

            bf16x8 bh[4], bl[4];
#pragma unroll
            for (int nf = 0; nf < 4; ++nf) {
                int n = wn + nf * 16 + l15;
                bh[nf] = *(const bf16x8*)&Bhi[n * 32 + quad * 8];
                bl[nf] = *(const bf16x8*)&Blo[n * 32 + quad * 8];
            }

#pragma unroll
            for (int mf = 0; mf < 4; ++mf) {
                float xv = Xs[quad][wm + mf * 16 + l15];
                u32x4 AH, AL;
                uint2 p;
                p = split2(e[mf][0] * xv, e[mf][1] * xv); AH.x = p.x; AL.x = p.y;
                p = split2(e[mf][2] * xv, e[mf][3] * xv); AH.y = p.x; AL.y = p.y;
                p = split2(e[mf][4] * xv, e[mf][5] * xv); AH.z = p.x; AL.z = p.y;
                p = split2(e[mf][6] * xv, e[mf][7] * xv); AH.w = p.x; AL.w = p.y;
                bf16x8 Ah = __builtin_bit_cast(bf16x8, AH);
                bf16x8 Al = __builtin_bit_cast(bf16x8, AL);
#pragma unroll
                for (int nf = 0; nf < 4; ++nf) {
                    acc[mf][nf] = __builtin_amdgcn_mfma_f32_16x16x32_bf16(Ah, bh[nf], acc[mf][nf], 0, 0, 0);
                    acc[mf][nf] = __builtin_amdgcn_mfma_f32_16x16x32_bf16(Ah, bl[nf], acc[mf][nf], 0, 0, 0);
                    acc[mf][nf] = __builtin_amdgcn_mfma_f32_16x16x32_bf16(Al, bh[nf], acc[mf][nf], 0, 0, 0);
                }
            }
        }
    }

#pragma unroll
    for (int nf = 0; nf < 4; ++nf) {
        int col = o0 + wn + nf * 16 + l15;
        float bv = bias[i * LOUT + col];
#pragma unroll
        for (int mf = 0; mf < 4; ++mf) {
#pragma unroll
            for (int reg = 0; reg < 4; ++reg) {
                int row = b0 + wm + mf * 16 + quad * 4 + reg;
                out[(size_t)row * D_OUT + i * LOUT + col] = acc[mf][nf][reg] + bv;
            }
        }
    }
}

extern "C" void kernel_launch(void* const* d_in, const int* in_sizes, int n_in,
                              void* d_out, int out_size, void* d_ws, size_t ws_size,
                              hipStream_t stream) {
    const float* x    = (const float*)d_in[0];
    const float* g0   = (const float*)d_in[1];
    const float* g1   = (const float*)d_in[2];
    const float* g2   = (const float*)d_in[3];
    const float* g3   = (const float*)d_in[4];
    const float* bias = (const float*)d_in[5];
    float* out = (float*)d_out;
    float* ws = (float*)d_ws;

    float* xT   = ws + WS_XT;
    float* ghat = ws + WS_GHAT;
    float* S    = ws + WS_S;
    float* envT = ws + WS_ENVT;

    k_transpose<<<dim3(128, 64), dim3(32, 8), 0, stream>>>(x, xT);
    k_reduce_g<<<dim3(16, 8, 4), 256, 0, stream>>>(g0, g1, g2, g3, ghat);
    k_s<<<dim3(1024, 4), 256, 0, stream>>>(x, ghat, S);
    k_env<<<1024, 256, 0, stream>>>(S, envT);

    if (ws_size >= (size_t)WS_NEED_BYTES) {
        short* ghi = (short*)(ws + WS_GSPL);
        short* glo = ghi + GSPL_PLANE;
        // 67,108,864 elems total, 8/thread, 256 threads/block -> 32768 blocks
        k_split_g<<<32768, 256, 0, stream>>>(g0, g1, g2, g3, ghi, glo);
        k_gemm2<<<512, 256, 0, stream>>>(ghi, glo, xT, envT, bias, out);
    } else {
        k_gemm_mfma<<<512, 256, 0, stream>>>(g0, g1, g2, g3, xT, envT, bias, out);
    }
}